// Round 6
// baseline (5589.795 us; speedup 1.0000x reference)
//
#include <hip/hip_runtime.h>
#include <stdint.h>

// Problem dims (fixed by setup_inputs)
#define BB 8
#define SS 2048
#define DD 1024
#define HH 4096
#define MM 256

typedef short bf16x8 __attribute__((ext_vector_type(8)));   // 8 bf16 in 4 VGPRs
typedef float f32x4 __attribute__((ext_vector_type(4)));

__device__ inline unsigned short f2bf(float f){
  unsigned u = __builtin_bit_cast(unsigned, f);
  return (unsigned short)((u + 0x7FFFu + ((u >> 16) & 1u)) >> 16);  // RNE
}

// ---------------- pack f32 -> bf16 (4 elems/thread) ----------------
__global__ void ssma_pack_bf16(const float* __restrict__ src,
                               unsigned short* __restrict__ dst, int n4){
  int i = blockIdx.x * blockDim.x + threadIdx.x;
  if (i < n4){
    float4 v = ((const float4*)src)[i];
    ushort4 o;
    o.x = f2bf(v.x); o.y = f2bf(v.y); o.z = f2bf(v.z); o.w = f2bf(v.w);
    ((ushort4*)dst)[i] = o;
  }
}

// ---------------- bf16 MFMA GEMM, C = A * B^T (+epilogue) ----------------
template<int EPI>
__global__ __launch_bounds__(256) void ssma_gemm_bt(
    const unsigned short* __restrict__ A, const unsigned short* __restrict__ Bw,
    int K, int N, const float* __restrict__ bias,
    const float* __restrict__ resid, void* __restrict__ Cout)
{
  __shared__ uint4 As4[512];   // 128x32 bf16 = 8KB
  __shared__ uint4 Bs4[512];
  unsigned short* As = (unsigned short*)As4;
  unsigned short* Bs = (unsigned short*)Bs4;

  const int tid  = threadIdx.x;
  const int lane = tid & 63;
  const int wv   = tid >> 6;
  const int wm   = wv >> 1, wn = wv & 1;      // 2x2 wave grid, 64x64 per wave
  const int m0   = blockIdx.y * 128;
  const int n0   = blockIdx.x * 128;
  const int kq   = lane >> 4;
  const int rl   = lane & 15;

  f32x4 acc[4][4];
#pragma unroll
  for (int a = 0; a < 4; ++a)
#pragma unroll
    for (int b = 0; b < 4; ++b) acc[a][b] = (f32x4){0.f, 0.f, 0.f, 0.f};

  for (int k0 = 0; k0 < K; k0 += 32){
    __syncthreads();
#pragma unroll
    for (int i = 0; i < 2; ++i){
      int c  = tid + 256 * i;
      int r  = c >> 2;
      int c8 = (c & 3) * 8;
      As4[c] = *(const uint4*)(A  + (size_t)(m0 + r) * K + k0 + c8);
      Bs4[c] = *(const uint4*)(Bw + (size_t)(n0 + r) * K + k0 + c8);
    }
    __syncthreads();

    const bf16x8* Ap = (const bf16x8*)As;
    const bf16x8* Bp = (const bf16x8*)Bs;
    bf16x8 af[4], bfr[4];
#pragma unroll
    for (int mi = 0; mi < 4; ++mi) af[mi]  = Ap[(wm * 64 + mi * 16 + rl) * 4 + kq];
#pragma unroll
    for (int ni = 0; ni < 4; ++ni) bfr[ni] = Bp[(wn * 64 + ni * 16 + rl) * 4 + kq];
#pragma unroll
    for (int mi = 0; mi < 4; ++mi)
#pragma unroll
      for (int ni = 0; ni < 4; ++ni)
        acc[mi][ni] = __builtin_amdgcn_mfma_f32_16x16x32_bf16(af[mi], bfr[ni], acc[mi][ni], 0, 0, 0);
  }

#pragma unroll
  for (int mi = 0; mi < 4; ++mi){
#pragma unroll
    for (int ni = 0; ni < 4; ++ni){
      int col = n0 + wn * 64 + ni * 16 + rl;
      float bv = bias[col];
#pragma unroll
      for (int r = 0; r < 4; ++r){
        int row = m0 + wm * 64 + mi * 16 + kq * 4 + r;
        float v = acc[mi][ni][r] + bv;
        if (EPI == 0){
          v = fmaxf(v, 0.0f);
          ((unsigned short*)Cout)[(size_t)row * N + col] = f2bf(v);
        } else {
          v += resid[(size_t)row * N + col];
          ((float*)Cout)[(size_t)row * N + col] = v;
        }
      }
    }
  }
}

// ---------------- exact-f32 GEMM: xproj = x * win_w^T + win_b ----------------
__global__ __launch_bounds__(256) void ssma_gemm3_f32(
    const float* __restrict__ A, const float* __restrict__ Bw,
    const float* __restrict__ bias, float* __restrict__ C)
{
  __shared__ float As[64][17];
  __shared__ float Bs[64][17];
  const int tid = threadIdx.x;
  const int tx = tid & 15, ty = tid >> 4;
  const int m0 = blockIdx.y * 64, n0 = blockIdx.x * 64;
  float acc[4][4];
#pragma unroll
  for (int i = 0; i < 4; ++i)
#pragma unroll
    for (int j = 0; j < 4; ++j) acc[i][j] = 0.f;

  for (int k0 = 0; k0 < DD; k0 += 16){
    __syncthreads();
#pragma unroll
    for (int i = 0; i < 4; ++i){
      int e = tid + 256 * i;
      int r = e >> 4, c = e & 15;
      As[r][c] = A [(size_t)(m0 + r) * DD + k0 + c];
      Bs[r][c] = Bw[(size_t)(n0 + r) * DD + k0 + c];
    }
    __syncthreads();
#pragma unroll
    for (int kk = 0; kk < 16; ++kk){
      float a[4], b[4];
#pragma unroll
      for (int i = 0; i < 4; ++i) a[i] = As[ty * 4 + i][kk];
#pragma unroll
      for (int j = 0; j < 4; ++j) b[j] = Bs[tx * 4 + j][kk];
#pragma unroll
      for (int i = 0; i < 4; ++i)
#pragma unroll
        for (int j = 0; j < 4; ++j) acc[i][j] = fmaf(a[i], b[j], acc[i][j]);
    }
  }
#pragma unroll
  for (int i = 0; i < 4; ++i){
    int row = m0 + ty * 4 + i;
#pragma unroll
    for (int j = 0; j < 4; ++j){
      int col = n0 + tx * 4 + j;
      C[(size_t)row * MM + col] = acc[i][j] + bias[col];
    }
  }
}

// ---------------- 256x256 f32 transpose (wstate -> wT) ----------------
__global__ __launch_bounds__(256) void ssma_transpose(
    const float* __restrict__ A, float* __restrict__ At)
{
  __shared__ float t[32][33];
  const int tx = threadIdx.x & 31, ty = threadIdx.x >> 5;  // 32x8
  const int x0 = blockIdx.x * 32, y0 = blockIdx.y * 32;
#pragma unroll
  for (int r = 0; r < 32; r += 8)
    t[ty + r][tx] = A[(size_t)(y0 + ty + r) * MM + x0 + tx];
  __syncthreads();
#pragma unroll
  for (int r = 0; r < 32; r += 8)
    At[(size_t)(x0 + ty + r) * MM + y0 + tx] = t[tx][ty + r];
}

// ---------------- sequential top-k gated scan, v5 ----------------
// 8 blocks x 1024 threads, __launch_bounds__(1024,4) -> 128 VGPR budget so all
// 32 matvec gathers stay in flight (round-5 had VGPR=48 -> serialized trips).
// 3 barriers/step:
//   A (tid<256): su[m] = relu(xp + sum_s wT[j_s*256+m]*g_s), coalesced gathers,
//     all 32 slots in one load batch; write su_all.  B1.
//   B (all): STATIC fully-unrolled strict-rank sweep of su_all[256] (zeros
//     can't outrank positives, so no compaction needed); 4 slices/row, combine
//     via 2 shfl_xor; gate g; per-wave kept-ballot -> kmask16.  B2.
//   C (all): 16-wave prefix over kmask16, owners write kept list (idx<<8,val),
//     zero-pad to nkp (>=32, mult 16).  B3.
__global__ __launch_bounds__(1024, 4) void ssma_scan5(
    const float* __restrict__ xproj, const float* __restrict__ state,
    const float* __restrict__ wT, const float* __restrict__ gamma_p,
    const int* __restrict__ topk_p, float* __restrict__ mem_out)
{
  __shared__ __align__(16) float su_all[MM];
  __shared__ __align__(16) int   kidx[MM + 32];    // j<<8 (float offset of wT row)
  __shared__ __align__(16) float kval[MM + 32];
  __shared__ __align__(16) unsigned long long umask[4];
  __shared__ __align__(16) int   kmask16[16];      // per-wave kept counts

  const int tid  = threadIdx.x;
  const int wv   = tid >> 6;
  const int lane = tid & 63;
  const int b    = blockIdx.x;
  const float gamma = *gamma_p;
  const float omg   = 1.0f - gamma;
  const int   rk    = *topk_p - 1;

  const int r = tid >> 2;         // rank row (all threads)
  const int q = tid & 3;          // rank slice

  const float* xp  = xproj + (size_t)b * SS * MM;
  const float* wTm = wT + tid;    // column base for matvec (tid<256 only)

  float mem = state[b * MM + r];  // q==0 threads own row r

  // ---- initial kept list from state (general: nonzero state handled) ----
  float st0 = 0.0f;
  if (tid < MM){
    st0 = state[b * MM + tid];
    unsigned long long pmi = __ballot(st0 != 0.0f);
    if (lane == 0) umask[wv] = pmi;
  }
  __syncthreads();
  int nkp;
  {
    unsigned long long u0 = umask[0], u1 = umask[1], u2 = umask[2], u3 = umask[3];
    int nk = __popcll(u0) + __popcll(u1) + __popcll(u2) + __popcll(u3);
    if (tid < MM && st0 != 0.0f){
      int before = (wv > 0 ? __popcll(u0) : 0) + (wv > 1 ? __popcll(u1) : 0)
                 + (wv > 2 ? __popcll(u2) : 0);
      unsigned long long mw = (wv == 0 ? u0 : wv == 1 ? u1 : wv == 2 ? u2 : u3);
      int pos = before + __popcll(mw & ((1ull << lane) - 1ull));
      kidx[pos] = tid << 8;
      kval[pos] = st0;
    }
    nkp = (nk + 15) & ~15; if (nkp < 32) nkp = 32;
    if (tid >= MM && tid < MM + 64){
      int t2 = tid - MM;
      if (nk + t2 < nkp){ kidx[nk + t2] = 0; kval[nk + t2] = 0.0f; }
    }
  }
  float xp_cur = (tid < MM) ? xp[tid] : 0.0f;
  __syncthreads();

  for (int t = 0; t < SS; ++t){
    // ================= phase A: matvec (waves 0-3) =================
    float xp_next = 0.0f;
    if (tid < MM){
      int tn = (t + 1 < SS) ? t + 1 : SS - 1;
      xp_next = xp[(size_t)tn * MM + tid];      // independent prefetch

      const int4*   ip = (const int4*)kidx;
      const float4* vp = (const float4*)kval;
      int4   I[8];
      float4 V[8];
#pragma unroll
      for (int j = 0; j < 8; ++j){ I[j] = ip[j]; V[j] = vp[j]; }
      float a0=0.f,a1=0.f,a2=0.f,a3=0.f,a4=0.f,a5=0.f,a6=0.f,a7=0.f;
      // 32 gathers issue as one batch (128-VGPR budget)
      float w00=wTm[I[0].x], w01=wTm[I[0].y], w02=wTm[I[0].z], w03=wTm[I[0].w];
      float w10=wTm[I[1].x], w11=wTm[I[1].y], w12=wTm[I[1].z], w13=wTm[I[1].w];
      float w20=wTm[I[2].x], w21=wTm[I[2].y], w22=wTm[I[2].z], w23=wTm[I[2].w];
      float w30=wTm[I[3].x], w31=wTm[I[3].y], w32=wTm[I[3].z], w33=wTm[I[3].w];
      float w40=wTm[I[4].x], w41=wTm[I[4].y], w42=wTm[I[4].z], w43=wTm[I[4].w];
      float w50=wTm[I[5].x], w51=wTm[I[5].y], w52=wTm[I[5].z], w53=wTm[I[5].w];
      float w60=wTm[I[6].x], w61=wTm[I[6].y], w62=wTm[I[6].z], w63=wTm[I[6].w];
      float w70=wTm[I[7].x], w71=wTm[I[7].y], w72=wTm[I[7].z], w73=wTm[I[7].w];
      a0=fmaf(w00,V[0].x,a0); a0=fmaf(w01,V[0].y,a0); a0=fmaf(w02,V[0].z,a0); a0=fmaf(w03,V[0].w,a0);
      a1=fmaf(w10,V[1].x,a1); a1=fmaf(w11,V[1].y,a1); a1=fmaf(w12,V[1].z,a1); a1=fmaf(w13,V[1].w,a1);
      a2=fmaf(w20,V[2].x,a2); a2=fmaf(w21,V[2].y,a2); a2=fmaf(w22,V[2].z,a2); a2=fmaf(w23,V[2].w,a2);
      a3=fmaf(w30,V[3].x,a3); a3=fmaf(w31,V[3].y,a3); a3=fmaf(w32,V[3].z,a3); a3=fmaf(w33,V[3].w,a3);
      a4=fmaf(w40,V[4].x,a4); a4=fmaf(w41,V[4].y,a4); a4=fmaf(w42,V[4].z,a4); a4=fmaf(w43,V[4].w,a4);
      a5=fmaf(w50,V[5].x,a5); a5=fmaf(w51,V[5].y,a5); a5=fmaf(w52,V[5].z,a5); a5=fmaf(w53,V[5].w,a5);
      a6=fmaf(w60,V[6].x,a6); a6=fmaf(w61,V[6].y,a6); a6=fmaf(w62,V[6].z,a6); a6=fmaf(w63,V[6].w,a6);
      a7=fmaf(w70,V[7].x,a7); a7=fmaf(w71,V[7].y,a7); a7=fmaf(w72,V[7].z,a7); a7=fmaf(w73,V[7].w,a7);
      // rare overflow (ties pushed kept count past 32)
      if (nkp > 32){
        for (int c4 = 8; c4 < (nkp >> 2); ++c4){
          int4 I2 = ip[c4]; float4 V2 = vp[c4];
          a0 = fmaf(wTm[I2.x], V2.x, a0); a1 = fmaf(wTm[I2.y], V2.y, a1);
          a2 = fmaf(wTm[I2.z], V2.z, a2); a3 = fmaf(wTm[I2.w], V2.w, a3);
        }
      }
      float s = ((a0 + a1) + (a2 + a3)) + ((a4 + a5) + (a6 + a7));
      su_all[tid] = fmaxf(s + xp_cur, 0.0f);
    }
    __syncthreads();   // B1: su_all ready

    // ================= phase B: static strict-rank sweep =================
    float su2 = su_all[r];
    int cnt = 0;
    const float4* spp = (const float4*)su_all;
#pragma unroll
    for (int i = 0; i < 16; ++i){
      float4 v = spp[i * 4 + q];          // 4-address broadcast per wave
      cnt += (v.x > su2) + (v.y > su2) + (v.z > su2) + (v.w > su2);
    }
    cnt += __shfl_xor(cnt, 1);
    cnt += __shfl_xor(cnt, 2);

    float g = (su2 > 0.0f && cnt <= rk) ? su2 : 0.0f;
    if (q == 0) mem = fmaf(gamma, mem, omg * g);

    unsigned long long kb = __ballot(q == 0 && g > 0.0f);
    unsigned long long kbS = kb & 0x1111111111111111ull;
    if (lane == 0) kmask16[wv] = __popcll(kbS);
    __syncthreads();   // B2: kmask16 ready

    // ================= phase C: kept-list write =================
    {
      int4 k0 = *(const int4*)&kmask16[0];
      int4 k1 = *(const int4*)&kmask16[4];
      int4 k2 = *(const int4*)&kmask16[8];
      int4 k3 = *(const int4*)&kmask16[12];
      int cw[16] = {k0.x,k0.y,k0.z,k0.w, k1.x,k1.y,k1.z,k1.w,
                    k2.x,k2.y,k2.z,k2.w, k3.x,k3.y,k3.z,k3.w};
      int nk = 0, before = 0;
#pragma unroll
      for (int w = 0; w < 16; ++w){
        nk += cw[w];
        if (w < wv) before += cw[w];
      }
      if (q == 0 && g > 0.0f){
        int pos = before + __popcll(kbS & ((1ull << lane) - 1ull));
        kidx[pos] = r << 8;
        kval[pos] = g;
      }
      nkp = (nk + 15) & ~15; if (nkp < 32) nkp = 32;
      if (tid < 64){
        if (nk + tid < nkp){ kidx[nk + tid] = 0; kval[nk + tid] = 0.0f; }
      }
    }
    xp_cur = xp_next;
    __syncthreads();   // B3: kept list ready for next matvec
  }
  if (q == 0) mem_out[b * MM + r] = mem;
}

extern "C" void kernel_launch(void* const* d_in, const int* in_sizes, int n_in,
                              void* d_out, int out_size, void* d_ws, size_t ws_size,
                              hipStream_t stream)
{
  const float* x      = (const float*)d_in[0];
  const float* state  = (const float*)d_in[1];
  // d_in[2]=U_w, d_in[3]=V_w unused by the reference
  const float* w1     = (const float*)d_in[4];
  const float* b1     = (const float*)d_in[5];
  const float* w2     = (const float*)d_in[6];
  const float* b2     = (const float*)d_in[7];
  const float* win_w  = (const float*)d_in[8];
  const float* win_b  = (const float*)d_in[9];
  const float* wstate = (const float*)d_in[10];
  const float* gammap = (const float*)d_in[11];
  const int*   topkp  = (const int*)d_in[12];

  float* out  = (float*)d_out;                       // (8,2048,1024)
  float* memo = out + (size_t)BB * SS * DD;          // (8,256)

  char* ws = (char*)d_ws;
  unsigned short* xb   = (unsigned short*)(ws);                   // 32 MB
  unsigned short* w1b  = (unsigned short*)(ws + 33554432);        // 8 MB (reused for wT after gemm1)
  unsigned short* w2b  = (unsigned short*)(ws + 41943040);        // 8 MB
  unsigned short* hbuf = (unsigned short*)(ws + 50331648);        // 128 MB
  float*          xprj = (float*)(ws + 184549376);                // 16 MB
  float*          wT   = (float*)(ws + 33554432);                 // 256 KB, after gemm1

  ssma_pack_bf16<<<16384, 256, 0, stream>>>(x,  xb,  4194304);
  ssma_pack_bf16<<<4096,  256, 0, stream>>>(w1, w1b, 1048576);
  ssma_pack_bf16<<<4096,  256, 0, stream>>>(w2, w2b, 1048576);

  ssma_gemm3_f32<<<dim3(4, 256), 256, 0, stream>>>(x, win_w, win_b, xprj);

  // h = relu(x*w1^T + b1): M=16384, N=4096, K=1024
  ssma_gemm_bt<0><<<dim3(32, 128), 256, 0, stream>>>(xb, w1b, 1024, 4096, b1, nullptr, (void*)hbuf);

  // wT = wstate^T (w1b region is dead after gemm1)
  ssma_transpose<<<dim3(8, 8), 256, 0, stream>>>(wstate, wT);

  // out = x + h*w2^T + b2: M=16384, N=1024, K=4096
  ssma_gemm_bt<1><<<dim3(8, 128), 256, 0, stream>>>(hbuf, w2b, 4096, 1024, b2, x, (void*)out);

  ssma_scan5<<<BB, 1024, 0, stream>>>(xprj, state, wT, gammap, topkp, memo);
}